// Round 7
// baseline (353.559 us; speedup 1.0000x reference)
//
#include <hip/hip_runtime.h>
#include <cmath>

#define LL 2048
#define NROW 8192
#define DMODEL 1024
#define DINNER 2048
#define NSTATE 16
#define NSEG 256
#define SEGLEN 8   // NSEG * SEGLEN == LL

typedef unsigned short u16;
typedef __attribute__((ext_vector_type(8))) unsigned short u16x8;
typedef __attribute__((ext_vector_type(8))) short short8;
typedef __attribute__((ext_vector_type(4))) float floatx4;
typedef __attribute__((ext_vector_type(16))) float floatx16;

__device__ __forceinline__ float bf2f(u16 h) {
    unsigned u = ((unsigned)h) << 16;
    float f;
    __builtin_memcpy(&f, &u, 4);
    return f;
}
__device__ __forceinline__ u16 f2bf(float f) {
    unsigned u;
    __builtin_memcpy(&u, &f, 4);
    u = u + 0x7fffu + ((u >> 16) & 1u);
    return (u16)(u >> 16);
}
__device__ __forceinline__ float silu_f(float x) { return x / (1.f + __expf(-x)); }
// bit-swap swizzle: rows r and r+2 get disjoint slot-sets (R5 conflict fix)
__device__ __forceinline__ int swz_pi(int r) {
    return (((r >> 1) & 1) << 1) | ((r >> 2) & 1);
}

// One kernel converts all six fp32->bf16 tensors (2048 elems per block).
__global__ __launch_bounds__(256) void cvt_multi(
    const float* __restrict__ s0, const float* __restrict__ s1,
    const float* __restrict__ s2, const float* __restrict__ s3,
    const float* __restrict__ s4, const float* __restrict__ s5,
    u16* __restrict__ d0, u16* __restrict__ d1, u16* __restrict__ d2,
    u16* __restrict__ d3, u16* __restrict__ d4, u16* __restrict__ d5) {
    int bid = blockIdx.x;
    const float* s;
    u16* d;
    size_t off;
    if (bid < 4096)      { s = s0; d = d0; off = (size_t)bid * 2048; }
    else if (bid < 6144) { s = s1; d = d1; off = (size_t)(bid - 4096) * 2048; }
    else if (bid < 7168) { s = s2; d = d2; off = (size_t)(bid - 6144) * 2048; }
    else if (bid < 7184) { s = s3; d = d3; off = (size_t)(bid - 7168) * 2048; }
    else if (bid < 7200) { s = s4; d = d4; off = (size_t)(bid - 7184) * 2048; }
    else                 { s = s5; d = d5; off = (size_t)(bid - 7200) * 2048; }
    size_t i = off + (size_t)threadIdx.x * 8;
    float4 a = *(const float4*)&s[i];
    float4 b = *(const float4*)&s[i + 4];
    u16x8 o;
    o[0] = f2bf(a.x); o[1] = f2bf(a.y); o[2] = f2bf(a.z); o[3] = f2bf(a.w);
    o[4] = f2bf(b.x); o[5] = f2bf(b.y); o[6] = f2bf(b.z); o[7] = f2bf(b.w);
    *(u16x8*)&d[i] = o;
}

// C[m][n] = sum_k A[m,k]*B[n,k]; A: MxK bf16, B: NxK bf16, row-major.
// 128x128 tile, BK=32, 4 waves (2x2), each wave 64x64 via 2x2 of 32x32x16 MFMA.
// LDS slot swizzle: slot = kb ^ pi[(row>>1)&3], pi={0,2,1,3}.
template <int OUT_BF16>
__global__ __launch_bounds__(256) void gemm_bt_mfma(
    const u16* __restrict__ A, const u16* __restrict__ B,
    void* __restrict__ Cout, int N, int K) {
    __shared__ u16 As[128 * 32];
    __shared__ u16 Bs[128 * 32];
    const int tid = threadIdx.x;
    const int lane = tid & 63;
    const int wave = tid >> 6;
    const int bm = blockIdx.y * 128;
    const int bn = blockIdx.x * 128;

    // staging: chunk c=wave*2+p covers tile rows [c*16, c*16+16)
    const int srow = lane >> 2;
    const int kbg = (lane & 3) ^ swz_pi(srow);
    const u16* ag[2];
    const u16* bg[2];
#pragma unroll
    for (int p = 0; p < 2; ++p) {
        int c = wave * 2 + p;
        ag[p] = A + (size_t)(bm + c * 16 + srow) * K + kbg * 8;
        bg[p] = B + (size_t)(bn + c * 16 + srow) * K + kbg * 8;
    }
    // fragment offsets
    const int frow = lane & 31;
    const int khi = lane >> 5;
    const int wr = (wave >> 1) * 64;
    const int wc = (wave & 1) * 64;
    const int fswz = swz_pi(frow);   // (wr+mi*32) is mult of 32 -> doesn't affect bits 1,2
    int aoff[2][2], boff[2][2];
#pragma unroll
    for (int mi = 0; mi < 2; ++mi)
#pragma unroll
        for (int kh = 0; kh < 2; ++kh) {
            int rA = wr + mi * 32 + frow;
            int rB = wc + mi * 32 + frow;
            int kb = kh * 2 + khi;
            aoff[mi][kh] = rA * 32 + (kb ^ fswz) * 8;
            boff[mi][kh] = rB * 32 + (kb ^ fswz) * 8;
        }
    floatx16 acc[2][2];
#pragma unroll
    for (int i = 0; i < 2; ++i)
#pragma unroll
        for (int j = 0; j < 2; ++j) acc[i][j] = (floatx16)(0.f);

    for (int k0 = 0; k0 < K; k0 += 32) {
        __syncthreads();
#pragma unroll
        for (int p = 0; p < 2; ++p) {
            int c = wave * 2 + p;
            __builtin_amdgcn_global_load_lds(
                (const __attribute__((address_space(1))) void*)ag[p],
                (__attribute__((address_space(3))) void*)&As[c * 512], 16, 0, 0);
            __builtin_amdgcn_global_load_lds(
                (const __attribute__((address_space(1))) void*)bg[p],
                (__attribute__((address_space(3))) void*)&Bs[c * 512], 16, 0, 0);
            ag[p] += 32;
            bg[p] += 32;
        }
        __syncthreads();
        short8 af[2][2], bf[2][2];
#pragma unroll
        for (int mi = 0; mi < 2; ++mi)
#pragma unroll
            for (int kh = 0; kh < 2; ++kh) {
                af[mi][kh] = *(const short8*)&As[aoff[mi][kh]];
                bf[mi][kh] = *(const short8*)&Bs[boff[mi][kh]];
            }
#pragma unroll
        for (int kh = 0; kh < 2; ++kh)
#pragma unroll
            for (int mi = 0; mi < 2; ++mi)
#pragma unroll
                for (int ni = 0; ni < 2; ++ni)
                    acc[mi][ni] = __builtin_amdgcn_mfma_f32_32x32x16_bf16(
                        af[mi][kh], bf[ni][kh], acc[mi][ni], 0, 0, 0);
    }
    // C/D layout (m74/m101): col = lane&31, row = (reg&3) + 8*(reg>>2) + 4*(lane>>5)
    const int cc = lane & 31;
    const int rbase = 4 * (lane >> 5);
#pragma unroll
    for (int mi = 0; mi < 2; ++mi)
#pragma unroll
        for (int ni = 0; ni < 2; ++ni)
#pragma unroll
            for (int r = 0; r < 16; ++r) {
                int grow = bm + wr + mi * 32 + (r & 3) + 8 * (r >> 2) + rbase;
                int gcol = bn + wc + ni * 32 + cc;
                float v = acc[mi][ni][r];
                if (OUT_BF16)
                    ((u16*)Cout)[(size_t)grow * N + gcol] = f2bf(v);
                else
                    ((float*)Cout)[(size_t)grow * N + gcol] = v;
            }
}

// depthwise causal conv (DC=4) + bias + silu + row-mean.
__global__ __launch_bounds__(256) void conv_silu_avg(
    const u16* __restrict__ xin, const float* __restrict__ cw,
    const float* __restrict__ cb, u16* __restrict__ xconv,
    float* __restrict__ xavg) {
    const int blk = blockIdx.x;        // 512 blocks
    const int b = blk >> 7;
    const int lc = blk & 127;
    const int row0 = b * LL + lc * 16;
    const int tid = threadIdx.x;
    const int lane = tid & 63, wave = tid >> 6;
    const int d0 = tid * 8;
    float4 cwv[8];
    float cbv[8];
#pragma unroll
    for (int e = 0; e < 8; ++e) cwv[e] = *(const float4*)&cw[(d0 + e) * 4];
#pragma unroll
    for (int e = 0; e < 8; e += 4) {
        float4 c = *(const float4*)&cb[d0 + e];
        cbv[e] = c.x; cbv[e + 1] = c.y; cbv[e + 2] = c.z; cbv[e + 3] = c.w;
    }
    u16x8 w0, w1, w2;
    if (lc == 0) {
        w0 = (u16x8)0; w1 = (u16x8)0; w2 = (u16x8)0;
    } else {
        w0 = *(const u16x8*)&xin[(size_t)(row0 - 3) * (2 * DINNER) + d0];
        w1 = *(const u16x8*)&xin[(size_t)(row0 - 2) * (2 * DINNER) + d0];
        w2 = *(const u16x8*)&xin[(size_t)(row0 - 1) * (2 * DINNER) + d0];
    }
    float sums[16];
#pragma unroll
    for (int t = 0; t < 16; ++t) {
        u16x8 cur = *(const u16x8*)&xin[(size_t)(row0 + t) * (2 * DINNER) + d0];
        float lsum = 0.f;
        u16x8 o;
#pragma unroll
        for (int e = 0; e < 8; ++e) {
            float acc = cbv[e];
            acc += bf2f(w0[e]) * cwv[e].x;
            acc += bf2f(w1[e]) * cwv[e].y;
            acc += bf2f(w2[e]) * cwv[e].z;
            acc += bf2f(cur[e]) * cwv[e].w;
            float s = silu_f(acc);
            lsum += s;
            o[e] = f2bf(s);
        }
        *(u16x8*)&xconv[(size_t)(row0 + t) * DINNER + d0] = o;
        sums[t] = lsum;
        w0 = w1; w1 = w2; w2 = cur;
    }
#pragma unroll
    for (int off = 32; off; off >>= 1)
#pragma unroll
        for (int t = 0; t < 16; ++t) sums[t] += __shfl_down(sums[t], off);
    __shared__ float wred[4][16];
    if (lane == 0) {
#pragma unroll
        for (int t = 0; t < 16; ++t) wred[wave][t] = sums[t];
    }
    __syncthreads();
    if (tid < 16)
        xavg[row0 + tid] = (wred[0][tid] + wred[1][tid] + wred[2][tid] + wred[3][tid]) *
                           (1.f / DINNER);
}

// delta/B/C projections via MFMA (16x16x32): thin GEMM (8192 x 48 x 2048).
__global__ __launch_bounds__(256) void dbc_mfma(
    const u16* __restrict__ xconv, const u16* __restrict__ wcat,
    const float* __restrict__ db, const float* __restrict__ A_log,
    const float* __restrict__ xavg,
    float* __restrict__ a_out, float* __restrict__ u_out, float* __restrict__ c_out) {
    __shared__ u16 As[128 * 32];
    __shared__ u16 Bs[48 * 32];
    const int tid = threadIdx.x;
    const int lane = tid & 63;
    const int wave = tid >> 6;
    const int bm = blockIdx.x * 128;

    const int kbg = (lane & 3) ^ ((lane >> 3) & 3);
    const int srow = lane >> 2;
    const u16* ag[2];
#pragma unroll
    for (int p = 0; p < 2; ++p) {
        int c = wave * 2 + p;
        ag[p] = xconv + (size_t)(bm + c * 16 + srow) * DINNER + kbg * 8;
    }
    const u16* bgp = wcat + (size_t)(wave * 16 + srow) * DINNER + kbg * 8;  // wave<3 only
    const int fr = lane & 15;
    const int kb = lane >> 4;
    const int kbs = kb ^ ((fr >> 1) & 3);
    int aoff[2], boff[3];
#pragma unroll
    for (int mi = 0; mi < 2; ++mi) aoff[mi] = (wave * 32 + mi * 16 + fr) * 32 + kbs * 8;
#pragma unroll
    for (int ni = 0; ni < 3; ++ni) boff[ni] = (ni * 16 + fr) * 32 + kbs * 8;

    floatx4 acc[2][3];
#pragma unroll
    for (int mi = 0; mi < 2; ++mi)
#pragma unroll
        for (int ni = 0; ni < 3; ++ni) acc[mi][ni] = (floatx4){0.f, 0.f, 0.f, 0.f};

    for (int k0 = 0; k0 < DINNER; k0 += 32) {
        __syncthreads();
#pragma unroll
        for (int p = 0; p < 2; ++p) {
            int c = wave * 2 + p;
            __builtin_amdgcn_global_load_lds(
                (const __attribute__((address_space(1))) void*)ag[p],
                (__attribute__((address_space(3))) void*)&As[c * 512], 16, 0, 0);
            ag[p] += 32;
        }
        if (wave < 3) {
            __builtin_amdgcn_global_load_lds(
                (const __attribute__((address_space(1))) void*)bgp,
                (__attribute__((address_space(3))) void*)&Bs[wave * 512], 16, 0, 0);
            bgp += 32;
        }
        __syncthreads();
        short8 af[2], bf[3];
#pragma unroll
        for (int mi = 0; mi < 2; ++mi) af[mi] = *(const short8*)&As[aoff[mi]];
#pragma unroll
        for (int ni = 0; ni < 3; ++ni) bf[ni] = *(const short8*)&Bs[boff[ni]];
#pragma unroll
        for (int mi = 0; mi < 2; ++mi)
#pragma unroll
            for (int ni = 0; ni < 3; ++ni)
                acc[mi][ni] = __builtin_amdgcn_mfma_f32_16x16x32_bf16(af[mi], bf[ni],
                                                                      acc[mi][ni], 0, 0, 0);
    }
    const int cr = (lane >> 4) * 4;
    const int s = lane & 15;
    const float Aa = -__expf(A_log[s]);
    const float dbs = db[s];
#pragma unroll
    for (int mi = 0; mi < 2; ++mi)
#pragma unroll
        for (int r = 0; r < 4; ++r) {
            int row = bm + wave * 32 + mi * 16 + cr + r;
            float pre = acc[mi][0][r] + dbs;
            float delta = (pre > 20.f) ? pre : log1pf(__expf(pre));
            a_out[row * NSTATE + s] = __expf(delta * Aa);
            u_out[row * NSTATE + s] = delta * acc[mi][1][r] * xavg[row];
            c_out[row * NSTATE + s] = acc[mi][2][r];
        }
}

// ---- parallel linear scan, 3 phases (NSEG=256, SEGLEN=8) ----
__global__ __launch_bounds__(256) void scan_p1(
    const float* __restrict__ a, const float* __restrict__ u,
    float* __restrict__ Pc, float* __restrict__ H0c) {
    int gid = blockIdx.x * 256 + threadIdx.x;
    int s = gid & 15, seg = (gid >> 4) & (NSEG - 1), b = gid >> 12;
    size_t base = (size_t)(b * LL + seg * SEGLEN) * NSTATE + s;
    float P = 1.f, h = 0.f;
#pragma unroll
    for (int t = 0; t < SEGLEN; ++t) {
        float av = a[base + (size_t)t * NSTATE];
        float uv = u[base + (size_t)t * NSTATE];
        h = fmaf(av, h, uv);
        P *= av;
    }
    int o = (b * NSEG + seg) * NSTATE + s;
    Pc[o] = P;
    H0c[o] = h;
}

__global__ __launch_bounds__(64) void scan_p2(
    const float* __restrict__ Pc, const float* __restrict__ H0c,
    float* __restrict__ hstart) {
    int lane = threadIdx.x;
    int b = lane >> 4, s = lane & 15;
    float h = 0.f;
#pragma unroll 8
    for (int seg = 0; seg < NSEG; ++seg) {
        int o = (b * NSEG + seg) * NSTATE + s;
        hstart[o] = h;
        h = fmaf(Pc[o], h, H0c[o]);
    }
}

__global__ __launch_bounds__(256) void scan_p3(
    const float* __restrict__ a, const float* __restrict__ u,
    const float* __restrict__ c, const float* __restrict__ hstart,
    float* __restrict__ y) {
    int gid = blockIdx.x * 256 + threadIdx.x;
    int s = gid & 15, seg = (gid >> 4) & (NSEG - 1), b = gid >> 12;
    float h = hstart[(b * NSEG + seg) * NSTATE + s];
    size_t base = (size_t)(b * LL + seg * SEGLEN) * NSTATE + s;
#pragma unroll
    for (int t = 0; t < SEGLEN; ++t) {
        float av = a[base + (size_t)t * NSTATE];
        float uv = u[base + (size_t)t * NSTATE];
        float cv = c[base + (size_t)t * NSTATE];
        h = fmaf(av, h, uv);
        float p = h * cv;
        p += __shfl_xor(p, 1);
        p += __shfl_xor(p, 2);
        p += __shfl_xor(p, 4);
        p += __shfl_xor(p, 8);
        if (s == 0) y[b * LL + seg * SEGLEN + t] = p;
    }
}

// y_skip = y*silu(x_gate) + x_conv*D  -> bf16
__global__ __launch_bounds__(256) void gate_skip(
    const u16* __restrict__ xin, const float* __restrict__ y,
    const float* __restrict__ Dv, const u16* __restrict__ xconv,
    u16* __restrict__ yskip) {
    size_t i = ((size_t)blockIdx.x * 256 + threadIdx.x) * 8;
    int row = (int)(i >> 11);
    int d = (int)(i & (DINNER - 1));
    u16x8 g = *(const u16x8*)&xin[(size_t)row * (2 * DINNER) + DINNER + d];
    u16x8 xc = *(const u16x8*)&xconv[i];
    float yv = y[row];
    u16x8 o;
#pragma unroll
    for (int e = 0; e < 8; ++e) {
        float gv = silu_f(bf2f(g[e]));
        float v = yv * gv + bf2f(xc[e]) * Dv[d + e];
        o[e] = f2bf(v);
    }
    *(u16x8*)&yskip[i] = o;
}

extern "C" void kernel_launch(void* const* d_in, const int* in_sizes, int n_in,
                              void* d_out, int out_size, void* d_ws, size_t ws_size,
                              hipStream_t stream) {
    const float* x       = (const float*)d_in[0];
    const float* w_in    = (const float*)d_in[1];
    const float* conv_w  = (const float*)d_in[2];
    const float* conv_b  = (const float*)d_in[3];
    const float* A_log   = (const float*)d_in[4];
    const float* Dv      = (const float*)d_in[5];
    const float* delta_w = (const float*)d_in[6];
    const float* delta_b = (const float*)d_in[7];
    const float* B_w     = (const float*)d_in[8];
    const float* C_w     = (const float*)d_in[9];
    const float* out_w   = (const float*)d_in[10];
    float* out = (float*)d_out;

    u16* xb  = (u16*)d_ws;                 // 8192*1024
    u16* wb  = xb + 8388608;               // 4096*1024
    u16* owb = wb + 4194304;               // 1024*2048
    u16* wsb = owb + 2097152;              // 48*2048 (concat dw,bw,cw)
    u16* xin = wsb + 98304;                // 8192*4096
    u16* xcv = xin + 33554432;             // 8192*2048
    u16* ysk = xcv + 16777216;             // 8192*2048
    float* fb     = (float*)(ysk + 16777216);
    float* abuf   = fb;                    // 8192*16
    float* ubuf   = abuf + 131072;
    float* cbuf   = ubuf + 131072;
    float* pbuf   = cbuf + 131072;         // 4*256*16
    float* h0buf  = pbuf + 16384;
    float* hsbuf  = h0buf + 16384;
    float* ybuf   = hsbuf + 16384;         // 8192
    float* avgbuf = ybuf + 8192;           // 8192

    cvt_multi<<<7216, 256, 0, stream>>>(x, w_in, out_w, delta_w, B_w, C_w,
                                        xb, wb, owb, wsb, wsb + 32768, wsb + 65536);

    // x_inner = x @ in_proj_w.T : (8192x1024)@(4096x1024)^T -> bf16
    gemm_bt_mfma<1><<<dim3(32, 64), 256, 0, stream>>>(xb, wb, xin, 2 * DINNER, DMODEL);

    conv_silu_avg<<<512, 256, 0, stream>>>(xin, conv_w, conv_b, xcv, avgbuf);
    dbc_mfma<<<64, 256, 0, stream>>>(xcv, wsb, delta_b, A_log, avgbuf,
                                     abuf, ubuf, cbuf);

    scan_p1<<<64, 256, 0, stream>>>(abuf, ubuf, pbuf, h0buf);
    scan_p2<<<1, 64, 0, stream>>>(pbuf, h0buf, hsbuf);
    scan_p3<<<64, 256, 0, stream>>>(abuf, ubuf, cbuf, hsbuf, ybuf);

    gate_skip<<<NROW * DINNER / 8 / 256, 256, 0, stream>>>(xin, ybuf, Dv, xcv, ysk);

    // out = y_skip @ out_proj_w.T : (8192x2048)@(1024x2048)^T -> fp32
    gemm_bt_mfma<0><<<dim3(8, 64), 256, 0, stream>>>(ysk, owb, out, DMODEL, DINNER);
}

// Round 8
// 347.917 us; speedup vs baseline: 1.0162x; 1.0162x over previous
//
#include <hip/hip_runtime.h>
#include <cmath>

#define LL 2048
#define NROW 8192
#define DMODEL 1024
#define DINNER 2048
#define NSTATE 16
#define NSEG 256
#define SEGLEN 8   // NSEG * SEGLEN == LL

typedef unsigned short u16;
typedef __attribute__((ext_vector_type(8))) unsigned short u16x8;
typedef __attribute__((ext_vector_type(8))) short short8;
typedef __attribute__((ext_vector_type(4))) float floatx4;
typedef __attribute__((ext_vector_type(16))) float floatx16;

__device__ __forceinline__ float bf2f(u16 h) {
    unsigned u = ((unsigned)h) << 16;
    float f;
    __builtin_memcpy(&f, &u, 4);
    return f;
}
__device__ __forceinline__ u16 f2bf(float f) {
    unsigned u;
    __builtin_memcpy(&u, &f, 4);
    u = u + 0x7fffu + ((u >> 16) & 1u);
    return (u16)(u >> 16);
}
__device__ __forceinline__ float silu_f(float x) { return x / (1.f + __expf(-x)); }

// One kernel converts all six fp32->bf16 tensors (2048 elems per block).
__global__ __launch_bounds__(256) void cvt_multi(
    const float* __restrict__ s0, const float* __restrict__ s1,
    const float* __restrict__ s2, const float* __restrict__ s3,
    const float* __restrict__ s4, const float* __restrict__ s5,
    u16* __restrict__ d0, u16* __restrict__ d1, u16* __restrict__ d2,
    u16* __restrict__ d3, u16* __restrict__ d4, u16* __restrict__ d5) {
    int bid = blockIdx.x;
    const float* s;
    u16* d;
    size_t off;
    if (bid < 4096)      { s = s0; d = d0; off = (size_t)bid * 2048; }
    else if (bid < 6144) { s = s1; d = d1; off = (size_t)(bid - 4096) * 2048; }
    else if (bid < 7168) { s = s2; d = d2; off = (size_t)(bid - 6144) * 2048; }
    else if (bid < 7184) { s = s3; d = d3; off = (size_t)(bid - 7168) * 2048; }
    else if (bid < 7200) { s = s4; d = d4; off = (size_t)(bid - 7184) * 2048; }
    else                 { s = s5; d = d5; off = (size_t)(bid - 7200) * 2048; }
    size_t i = off + (size_t)threadIdx.x * 8;
    float4 a = *(const float4*)&s[i];
    float4 b = *(const float4*)&s[i + 4];
    u16x8 o;
    o[0] = f2bf(a.x); o[1] = f2bf(a.y); o[2] = f2bf(a.z); o[3] = f2bf(a.w);
    o[4] = f2bf(b.x); o[5] = f2bf(b.y); o[6] = f2bf(b.z); o[7] = f2bf(b.w);
    *(u16x8*)&d[i] = o;
}

// C[m][n] = sum_k A[m,k]*B[n,k]; A: MxK bf16, B: NxK bf16, row-major.
// 128x128 tile, BK=32, 4 waves (2x2), each wave 64x64 via 2x2 of 32x32x16 MFMA.
// LDS slot swizzle: slot = kb ^ ((rc>>1)&3) ^ 2*((row>>4)&1).
// The chunk-parity XOR breaks the lane-i / lane-i+16 same-bank pairing that
// caused the constant 4-cyc/read conflict in R5-R7 (rc-only swizzles can't).
template <int OUT_BF16>
__global__ __launch_bounds__(256) void gemm_bt_mfma(
    const u16* __restrict__ A, const u16* __restrict__ B,
    void* __restrict__ Cout, int N, int K) {
    __shared__ u16 As[128 * 32];
    __shared__ u16 Bs[128 * 32];
    const int tid = threadIdx.x;
    const int lane = tid & 63;
    const int wave = tid >> 6;
    const int bm = blockIdx.y * 128;
    const int bn = blockIdx.x * 128;

    // staging: chunk c=wave*2+p covers tile rows [c*16, c*16+16); parity=(c&1)=p
    const int srow = lane >> 2;
    const u16* ag[2];
    const u16* bg[2];
#pragma unroll
    for (int p = 0; p < 2; ++p) {
        int c = wave * 2 + p;
        int kbg = (lane & 3) ^ ((srow >> 1) & 3) ^ (2 * (p & 1));
        ag[p] = A + (size_t)(bm + c * 16 + srow) * K + kbg * 8;
        bg[p] = B + (size_t)(bn + c * 16 + srow) * K + kbg * 8;
    }
    // fragment offsets: row rA = wr + mi*32 + frow; rc = frow&15,
    // parity = (frow>>4)&1 (wr, mi*32 don't touch bit 4)
    const int frow = lane & 31;
    const int khi = lane >> 5;
    const int wr = (wave >> 1) * 64;
    const int wc = (wave & 1) * 64;
    const int fswz = ((frow >> 1) & 3) ^ (2 * ((frow >> 4) & 1));
    int aoff[2][2], boff[2][2];
#pragma unroll
    for (int mi = 0; mi < 2; ++mi)
#pragma unroll
        for (int kh = 0; kh < 2; ++kh) {
            int rA = wr + mi * 32 + frow;
            int rB = wc + mi * 32 + frow;
            int kb = kh * 2 + khi;
            aoff[mi][kh] = rA * 32 + (kb ^ fswz) * 8;
            boff[mi][kh] = rB * 32 + (kb ^ fswz) * 8;
        }
    floatx16 acc[2][2];
#pragma unroll
    for (int i = 0; i < 2; ++i)
#pragma unroll
        for (int j = 0; j < 2; ++j) acc[i][j] = (floatx16)(0.f);

    for (int k0 = 0; k0 < K; k0 += 32) {
        __syncthreads();
#pragma unroll
        for (int p = 0; p < 2; ++p) {
            int c = wave * 2 + p;
            __builtin_amdgcn_global_load_lds(
                (const __attribute__((address_space(1))) void*)ag[p],
                (__attribute__((address_space(3))) void*)&As[c * 512], 16, 0, 0);
            __builtin_amdgcn_global_load_lds(
                (const __attribute__((address_space(1))) void*)bg[p],
                (__attribute__((address_space(3))) void*)&Bs[c * 512], 16, 0, 0);
            ag[p] += 32;
            bg[p] += 32;
        }
        __syncthreads();
        short8 af[2][2], bf[2][2];
#pragma unroll
        for (int mi = 0; mi < 2; ++mi)
#pragma unroll
            for (int kh = 0; kh < 2; ++kh) {
                af[mi][kh] = *(const short8*)&As[aoff[mi][kh]];
                bf[mi][kh] = *(const short8*)&Bs[boff[mi][kh]];
            }
#pragma unroll
        for (int kh = 0; kh < 2; ++kh)
#pragma unroll
            for (int mi = 0; mi < 2; ++mi)
#pragma unroll
                for (int ni = 0; ni < 2; ++ni)
                    acc[mi][ni] = __builtin_amdgcn_mfma_f32_32x32x16_bf16(
                        af[mi][kh], bf[ni][kh], acc[mi][ni], 0, 0, 0);
    }
    // C/D layout (m74/m101): col = lane&31, row = (reg&3) + 8*(reg>>2) + 4*(lane>>5)
    const int cc = lane & 31;
    const int rbase = 4 * (lane >> 5);
#pragma unroll
    for (int mi = 0; mi < 2; ++mi)
#pragma unroll
        for (int ni = 0; ni < 2; ++ni)
#pragma unroll
            for (int r = 0; r < 16; ++r) {
                int grow = bm + wr + mi * 32 + (r & 3) + 8 * (r >> 2) + rbase;
                int gcol = bn + wc + ni * 32 + cc;
                float v = acc[mi][ni][r];
                if (OUT_BF16)
                    ((u16*)Cout)[(size_t)grow * N + gcol] = f2bf(v);
                else
                    ((float*)Cout)[(size_t)grow * N + gcol] = v;
            }
}

// depthwise causal conv (DC=4) + bias + silu + row-mean.
__global__ __launch_bounds__(256) void conv_silu_avg(
    const u16* __restrict__ xin, const float* __restrict__ cw,
    const float* __restrict__ cb, u16* __restrict__ xconv,
    float* __restrict__ xavg) {
    const int blk = blockIdx.x;        // 512 blocks
    const int b = blk >> 7;
    const int lc = blk & 127;
    const int row0 = b * LL + lc * 16;
    const int tid = threadIdx.x;
    const int lane = tid & 63, wave = tid >> 6;
    const int d0 = tid * 8;
    float4 cwv[8];
    float cbv[8];
#pragma unroll
    for (int e = 0; e < 8; ++e) cwv[e] = *(const float4*)&cw[(d0 + e) * 4];
#pragma unroll
    for (int e = 0; e < 8; e += 4) {
        float4 c = *(const float4*)&cb[d0 + e];
        cbv[e] = c.x; cbv[e + 1] = c.y; cbv[e + 2] = c.z; cbv[e + 3] = c.w;
    }
    u16x8 w0, w1, w2;
    if (lc == 0) {
        w0 = (u16x8)0; w1 = (u16x8)0; w2 = (u16x8)0;
    } else {
        w0 = *(const u16x8*)&xin[(size_t)(row0 - 3) * (2 * DINNER) + d0];
        w1 = *(const u16x8*)&xin[(size_t)(row0 - 2) * (2 * DINNER) + d0];
        w2 = *(const u16x8*)&xin[(size_t)(row0 - 1) * (2 * DINNER) + d0];
    }
    float sums[16];
#pragma unroll
    for (int t = 0; t < 16; ++t) {
        u16x8 cur = *(const u16x8*)&xin[(size_t)(row0 + t) * (2 * DINNER) + d0];
        float lsum = 0.f;
        u16x8 o;
#pragma unroll
        for (int e = 0; e < 8; ++e) {
            float acc = cbv[e];
            acc += bf2f(w0[e]) * cwv[e].x;
            acc += bf2f(w1[e]) * cwv[e].y;
            acc += bf2f(w2[e]) * cwv[e].z;
            acc += bf2f(cur[e]) * cwv[e].w;
            float s = silu_f(acc);
            lsum += s;
            o[e] = f2bf(s);
        }
        *(u16x8*)&xconv[(size_t)(row0 + t) * DINNER + d0] = o;
        sums[t] = lsum;
        w0 = w1; w1 = w2; w2 = cur;
    }
#pragma unroll
    for (int off = 32; off; off >>= 1)
#pragma unroll
        for (int t = 0; t < 16; ++t) sums[t] += __shfl_down(sums[t], off);
    __shared__ float wred[4][16];
    if (lane == 0) {
#pragma unroll
        for (int t = 0; t < 16; ++t) wred[wave][t] = sums[t];
    }
    __syncthreads();
    if (tid < 16)
        xavg[row0 + tid] = (wred[0][tid] + wred[1][tid] + wred[2][tid] + wred[3][tid]) *
                           (1.f / DINNER);
}

// delta/B/C projections via MFMA (16x16x32): thin GEMM (8192 x 48 x 2048).
__global__ __launch_bounds__(256) void dbc_mfma(
    const u16* __restrict__ xconv, const u16* __restrict__ wcat,
    const float* __restrict__ db, const float* __restrict__ A_log,
    const float* __restrict__ xavg,
    float* __restrict__ a_out, float* __restrict__ u_out, float* __restrict__ c_out) {
    __shared__ u16 As[128 * 32];
    __shared__ u16 Bs[48 * 32];
    const int tid = threadIdx.x;
    const int lane = tid & 63;
    const int wave = tid >> 6;
    const int bm = blockIdx.x * 128;

    const int kbg = (lane & 3) ^ ((lane >> 3) & 3);
    const int srow = lane >> 2;
    const u16* ag[2];
#pragma unroll
    for (int p = 0; p < 2; ++p) {
        int c = wave * 2 + p;
        ag[p] = xconv + (size_t)(bm + c * 16 + srow) * DINNER + kbg * 8;
    }
    const u16* bgp = wcat + (size_t)(wave * 16 + srow) * DINNER + kbg * 8;  // wave<3 only
    const int fr = lane & 15;
    const int kb = lane >> 4;
    const int kbs = kb ^ ((fr >> 1) & 3);
    int aoff[2], boff[3];
#pragma unroll
    for (int mi = 0; mi < 2; ++mi) aoff[mi] = (wave * 32 + mi * 16 + fr) * 32 + kbs * 8;
#pragma unroll
    for (int ni = 0; ni < 3; ++ni) boff[ni] = (ni * 16 + fr) * 32 + kbs * 8;

    floatx4 acc[2][3];
#pragma unroll
    for (int mi = 0; mi < 2; ++mi)
#pragma unroll
        for (int ni = 0; ni < 3; ++ni) acc[mi][ni] = (floatx4){0.f, 0.f, 0.f, 0.f};

    for (int k0 = 0; k0 < DINNER; k0 += 32) {
        __syncthreads();
#pragma unroll
        for (int p = 0; p < 2; ++p) {
            int c = wave * 2 + p;
            __builtin_amdgcn_global_load_lds(
                (const __attribute__((address_space(1))) void*)ag[p],
                (__attribute__((address_space(3))) void*)&As[c * 512], 16, 0, 0);
            ag[p] += 32;
        }
        if (wave < 3) {
            __builtin_amdgcn_global_load_lds(
                (const __attribute__((address_space(1))) void*)bgp,
                (__attribute__((address_space(3))) void*)&Bs[wave * 512], 16, 0, 0);
            bgp += 32;
        }
        __syncthreads();
        short8 af[2], bf[3];
#pragma unroll
        for (int mi = 0; mi < 2; ++mi) af[mi] = *(const short8*)&As[aoff[mi]];
#pragma unroll
        for (int ni = 0; ni < 3; ++ni) bf[ni] = *(const short8*)&Bs[boff[ni]];
#pragma unroll
        for (int mi = 0; mi < 2; ++mi)
#pragma unroll
            for (int ni = 0; ni < 3; ++ni)
                acc[mi][ni] = __builtin_amdgcn_mfma_f32_16x16x32_bf16(af[mi], bf[ni],
                                                                      acc[mi][ni], 0, 0, 0);
    }
    const int cr = (lane >> 4) * 4;
    const int s = lane & 15;
    const float Aa = -__expf(A_log[s]);
    const float dbs = db[s];
#pragma unroll
    for (int mi = 0; mi < 2; ++mi)
#pragma unroll
        for (int r = 0; r < 4; ++r) {
            int row = bm + wave * 32 + mi * 16 + cr + r;
            float pre = acc[mi][0][r] + dbs;
            float delta = (pre > 20.f) ? pre : log1pf(__expf(pre));
            a_out[row * NSTATE + s] = __expf(delta * Aa);
            u_out[row * NSTATE + s] = delta * acc[mi][1][r] * xavg[row];
            c_out[row * NSTATE + s] = acc[mi][2][r];
        }
}

// ---- parallel linear scan, 3 phases (NSEG=256, SEGLEN=8) ----
__global__ __launch_bounds__(256) void scan_p1(
    const float* __restrict__ a, const float* __restrict__ u,
    float* __restrict__ Pc, float* __restrict__ H0c) {
    int gid = blockIdx.x * 256 + threadIdx.x;
    int s = gid & 15, seg = (gid >> 4) & (NSEG - 1), b = gid >> 12;
    size_t base = (size_t)(b * LL + seg * SEGLEN) * NSTATE + s;
    float P = 1.f, h = 0.f;
#pragma unroll
    for (int t = 0; t < SEGLEN; ++t) {
        float av = a[base + (size_t)t * NSTATE];
        float uv = u[base + (size_t)t * NSTATE];
        h = fmaf(av, h, uv);
        P *= av;
    }
    int o = (b * NSEG + seg) * NSTATE + s;
    Pc[o] = P;
    H0c[o] = h;
}

__global__ __launch_bounds__(64) void scan_p2(
    const float* __restrict__ Pc, const float* __restrict__ H0c,
    float* __restrict__ hstart) {
    int lane = threadIdx.x;
    int b = lane >> 4, s = lane & 15;
    float h = 0.f;
#pragma unroll 8
    for (int seg = 0; seg < NSEG; ++seg) {
        int o = (b * NSEG + seg) * NSTATE + s;
        hstart[o] = h;
        h = fmaf(Pc[o], h, H0c[o]);
    }
}

__global__ __launch_bounds__(256) void scan_p3(
    const float* __restrict__ a, const float* __restrict__ u,
    const float* __restrict__ c, const float* __restrict__ hstart,
    float* __restrict__ y) {
    int gid = blockIdx.x * 256 + threadIdx.x;
    int s = gid & 15, seg = (gid >> 4) & (NSEG - 1), b = gid >> 12;
    float h = hstart[(b * NSEG + seg) * NSTATE + s];
    size_t base = (size_t)(b * LL + seg * SEGLEN) * NSTATE + s;
#pragma unroll
    for (int t = 0; t < SEGLEN; ++t) {
        float av = a[base + (size_t)t * NSTATE];
        float uv = u[base + (size_t)t * NSTATE];
        float cv = c[base + (size_t)t * NSTATE];
        h = fmaf(av, h, uv);
        float p = h * cv;
        p += __shfl_xor(p, 1);
        p += __shfl_xor(p, 2);
        p += __shfl_xor(p, 4);
        p += __shfl_xor(p, 8);
        if (s == 0) y[b * LL + seg * SEGLEN + t] = p;
    }
}

// y_skip = y*silu(x_gate) + x_conv*D  -> bf16
__global__ __launch_bounds__(256) void gate_skip(
    const u16* __restrict__ xin, const float* __restrict__ y,
    const float* __restrict__ Dv, const u16* __restrict__ xconv,
    u16* __restrict__ yskip) {
    size_t i = ((size_t)blockIdx.x * 256 + threadIdx.x) * 8;
    int row = (int)(i >> 11);
    int d = (int)(i & (DINNER - 1));
    u16x8 g = *(const u16x8*)&xin[(size_t)row * (2 * DINNER) + DINNER + d];
    u16x8 xc = *(const u16x8*)&xconv[i];
    float yv = y[row];
    u16x8 o;
#pragma unroll
    for (int e = 0; e < 8; ++e) {
        float gv = silu_f(bf2f(g[e]));
        float v = yv * gv + bf2f(xc[e]) * Dv[d + e];
        o[e] = f2bf(v);
    }
    *(u16x8*)&yskip[i] = o;
}

extern "C" void kernel_launch(void* const* d_in, const int* in_sizes, int n_in,
                              void* d_out, int out_size, void* d_ws, size_t ws_size,
                              hipStream_t stream) {
    const float* x       = (const float*)d_in[0];
    const float* w_in    = (const float*)d_in[1];
    const float* conv_w  = (const float*)d_in[2];
    const float* conv_b  = (const float*)d_in[3];
    const float* A_log   = (const float*)d_in[4];
    const float* Dv      = (const float*)d_in[5];
    const float* delta_w = (const float*)d_in[6];
    const float* delta_b = (const float*)d_in[7];
    const float* B_w     = (const float*)d_in[8];
    const float* C_w     = (const float*)d_in[9];
    const float* out_w   = (const float*)d_in[10];
    float* out = (float*)d_out;

    u16* xb  = (u16*)d_ws;                 // 8192*1024
    u16* wb  = xb + 8388608;               // 4096*1024
    u16* owb = wb + 4194304;               // 1024*2048
    u16* wsb = owb + 2097152;              // 48*2048 (concat dw,bw,cw)
    u16* xin = wsb + 98304;                // 8192*4096
    u16* xcv = xin + 33554432;             // 8192*2048
    u16* ysk = xcv + 16777216;             // 8192*2048
    float* fb     = (float*)(ysk + 16777216);
    float* abuf   = fb;                    // 8192*16
    float* ubuf   = abuf + 131072;
    float* cbuf   = ubuf + 131072;
    float* pbuf   = cbuf + 131072;         // 4*256*16
    float* h0buf  = pbuf + 16384;
    float* hsbuf  = h0buf + 16384;
    float* ybuf   = hsbuf + 16384;         // 8192
    float* avgbuf = ybuf + 8192;           // 8192

    cvt_multi<<<7216, 256, 0, stream>>>(x, w_in, out_w, delta_w, B_w, C_w,
                                        xb, wb, owb, wsb, wsb + 32768, wsb + 65536);

    // x_inner = x @ in_proj_w.T : (8192x1024)@(4096x1024)^T -> bf16
    gemm_bt_mfma<1><<<dim3(32, 64), 256, 0, stream>>>(xb, wb, xin, 2 * DINNER, DMODEL);

    conv_silu_avg<<<512, 256, 0, stream>>>(xin, conv_w, conv_b, xcv, avgbuf);
    dbc_mfma<<<64, 256, 0, stream>>>(xcv, wsb, delta_b, A_log, avgbuf,
                                     abuf, ubuf, cbuf);

    scan_p1<<<64, 256, 0, stream>>>(abuf, ubuf, pbuf, h0buf);
    scan_p2<<<1, 64, 0, stream>>>(pbuf, h0buf, hsbuf);
    scan_p3<<<64, 256, 0, stream>>>(abuf, ubuf, cbuf, hsbuf, ybuf);

    gate_skip<<<NROW * DINNER / 8 / 256, 256, 0, stream>>>(xin, ybuf, Dv, xcv, ysk);

    // out = y_skip @ out_proj_w.T : (8192x2048)@(1024x2048)^T -> fp32
    gemm_bt_mfma<0><<<dim3(8, 64), 256, 0, stream>>>(ysk, owb, out, DMODEL, DINNER);
}